// Round 1
// baseline (881.661 us; speedup 1.0000x reference)
//
#include <hip/hip_runtime.h>
#include <hip/hip_bf16.h>

// FFTLinearLayerV2: out[split,b,n,h,w] = sum_k W[split*256+n, k] * X[k, b,h,w]
// where X[k<256] = adc_real[b,k,h,w], X[k>=256] = adc_imag[b,k-256,h,w].
// GEMM: M=512 (o), K=512, N=262144 (sites). bf16 MFMA, f32 accumulate.
//
// Weight symmetry: W = [[C, S], [-S, C]]  =>  W[o+256][k] = -W[o][k+256] (k<256)
//                                             W[o+256][k] =  W[o][k-256] (k>=256)
// => only top half [C|S] is packed (256 KB bf16 in d_ws); high rows reuse
//    the same fragments with a sign flip.

typedef __attribute__((ext_vector_type(8))) short short8;
typedef __attribute__((ext_vector_type(4))) float f32x4;

#define HWSZ 65536   // H*W
#define NCH  256
#define KTOT 512

__device__ __forceinline__ unsigned f2bf(float f) {
    unsigned u = __builtin_bit_cast(unsigned, f);
    // round-to-nearest-even to bf16, return in low 16 bits
    return (u + 0x7FFFu + ((u >> 16) & 1u)) >> 16;
}

// ---------------------------------------------------------------------------
// Kernel 1: pack top half of weight (o in [0,256)) into bf16 A-fragment order.
// Fragment block (p, t): p = o-tile (0..15), t = k-chunk of 32 (0..15).
// Lane L holds A[m = p*16 + (L&15)][k = t*32 + (L>>4)*8 + j], j=0..7,
// stored as 16 contiguous bytes at ws + ((p*16+t)*64 + L)*16.
// ---------------------------------------------------------------------------
__global__ void pack_weight(const float* __restrict__ Wt, short* __restrict__ wfrag) {
    const int T  = blockIdx.x * 256 + threadIdx.x;   // 64 blocks * 256 = 16384
    const int fb = T >> 6;          // 0..255  (p*16 + t)
    const int L  = T & 63;
    const int p  = fb >> 4;
    const int t  = fb & 15;
    const int o  = p * 16 + (L & 15);
    const int k  = t * 32 + (L >> 4) * 8;
    const float* src = Wt + (size_t)o * KTOT + k;
    const float4 v0 = *(const float4*)(src);
    const float4 v1 = *(const float4*)(src + 4);
    uint4 o4;
    o4.x = f2bf(v0.x) | (f2bf(v0.y) << 16);
    o4.y = f2bf(v0.z) | (f2bf(v0.w) << 16);
    o4.z = f2bf(v1.x) | (f2bf(v1.y) << 16);
    o4.w = f2bf(v1.z) | (f2bf(v1.w) << 16);
    *(uint4*)(wfrag + (size_t)fb * 512 + L * 8) = o4;
}

// ---------------------------------------------------------------------------
// Kernel 2: GEMM. One block = all 512 o  x  64 consecutive sites of one b.
// grid 4096 (= 4 b * 1024 site-tiles), block 256 (4 waves).
// Wave w: o in [w*64, w*64+64) and the mirrored [256+w*64, 256+w*64+64).
// LDS: X tile as bf16, layout addr(s,k) = s*512 + ((k>>3)^(s&7))*8 + (k&7)
// (ushort units). XOR swizzle: frag reads (b128) conflict-free (2-way),
// staging writes (b64) ~4-way.
// ---------------------------------------------------------------------------
__global__ __launch_bounds__(256, 2)
void fft_gemm(const float* __restrict__ Rg, const float* __restrict__ Ig,
              const short* __restrict__ wfrag, float* __restrict__ out) {
    __shared__ short lds[64 * 512];   // 64 KB

    const int bid = blockIdx.x;
    const int b   = bid >> 10;
    const int hw0 = (bid & 1023) << 6;
    const int tid = threadIdx.x;
    const int L   = tid & 63;
    const int w   = tid >> 6;

    // ---- stage X tile: global f32 -> bf16 -> LDS (k-contiguous rows) ----
    {
        const int q  = tid & 15;    // s-quad: s = 4q..4q+3
        const int kg = tid >> 4;    // 0..15
        #pragma unroll
        for (int pass = 0; pass < 8; ++pass) {
            const int k0 = pass * 64 + kg * 4;           // 4 consecutive k rows
            const float* src = (k0 < 256) ? Rg : Ig;
            const int krel = k0 & 255;
            const float* p0 = src + (size_t)(b * NCH + krel) * HWSZ + hw0 + q * 4;
            const float4 r0 = *(const float4*)(p0);
            const float4 r1 = *(const float4*)(p0 + HWSZ);
            const float4 r2 = *(const float4*)(p0 + 2 * HWSZ);
            const float4 r3 = *(const float4*)(p0 + 3 * HWSZ);
            const float* f0 = (const float*)&r0;
            const float* f1 = (const float*)&r1;
            const float* f2 = (const float*)&r2;
            const float* f3 = (const float*)&r3;
            #pragma unroll
            for (int c = 0; c < 4; ++c) {   // 4x4 in-register transpose
                uint2 pk;
                pk.x = f2bf(f0[c]) | (f2bf(f1[c]) << 16);
                pk.y = f2bf(f2[c]) | (f2bf(f3[c]) << 16);
                const int s = q * 4 + c;
                const int addr = s * 512 + ((k0 >> 3) ^ (s & 7)) * 8 + (k0 & 7);
                *(uint2*)(&lds[addr]) = pk;
            }
        }
    }
    __syncthreads();

    // ---- MFMA main loop (no barriers from here on) ----
    f32x4 accL[4][4];
    f32x4 accH[4][4];
    #pragma unroll
    for (int j = 0; j < 4; ++j)
        #pragma unroll
        for (int u = 0; u < 4; ++u) {
            accL[j][u] = (f32x4){0.f, 0.f, 0.f, 0.f};
            accH[j][u] = (f32x4){0.f, 0.f, 0.f, 0.f};
        }

    const int col = L & 15;
    const int rq  = L >> 4;   // 0..3

    for (int tp = 0; tp < 8; ++tp) {
        const int t0 = tp, t1 = tp + 8;
        short8 a0[4], a1[4], b0[4], b1[4];
        #pragma unroll
        for (int j = 0; j < 4; ++j) {
            const int p = w * 4 + j;
            a0[j] = *(const short8*)(wfrag + (size_t)((p * 16 + t0) * 512 + L * 8));
            a1[j] = *(const short8*)(wfrag + (size_t)((p * 16 + t1) * 512 + L * 8));
        }
        #pragma unroll
        for (int u = 0; u < 4; ++u) {
            const int sp = u * 16 + col;
            const int c0 = (t0 * 4 + rq) ^ (sp & 7);
            const int c1 = (t1 * 4 + rq) ^ (sp & 7);
            b0[u] = *(const short8*)(&lds[sp * 512 + c0 * 8]);
            b1[u] = *(const short8*)(&lds[sp * 512 + c1 * 8]);
        }
        #pragma unroll
        for (int j = 0; j < 4; ++j) {
            const short8 na1 = a1[j] ^ (short)0x8000;   // -W[o][k+256]
            #pragma unroll
            for (int u = 0; u < 4; ++u) {
                accL[j][u] = __builtin_amdgcn_mfma_f32_16x16x32_bf16(a0[j], b0[u], accL[j][u], 0, 0, 0);
                accL[j][u] = __builtin_amdgcn_mfma_f32_16x16x32_bf16(a1[j], b1[u], accL[j][u], 0, 0, 0);
                accH[j][u] = __builtin_amdgcn_mfma_f32_16x16x32_bf16(na1,   b0[u], accH[j][u], 0, 0, 0);
                accH[j][u] = __builtin_amdgcn_mfma_f32_16x16x32_bf16(a0[j], b1[u], accH[j][u], 0, 0, 0);
            }
        }
    }

    // ---- epilogue: D layout col=lane&15, row=(lane>>4)*4+reg ----
    const size_t outbase = (size_t)(b * NCH) * HWSZ + hw0;
    #pragma unroll
    for (int j = 0; j < 4; ++j) {
        const int obase = w * 64 + j * 16 + rq * 4;
        #pragma unroll
        for (int u = 0; u < 4; ++u) {
            const size_t so = outbase + u * 16 + col;
            #pragma unroll
            for (int r = 0; r < 4; ++r) {
                const size_t off = so + (size_t)(obase + r) * HWSZ;
                out[off] = accL[j][u][r];
                out[off + (size_t)1024 * HWSZ] = accH[j][u][r];  // split=1 half
            }
        }
    }
}

extern "C" void kernel_launch(void* const* d_in, const int* in_sizes, int n_in,
                              void* d_out, int out_size, void* d_ws, size_t ws_size,
                              hipStream_t stream) {
    const float* R  = (const float*)d_in[0];
    const float* I  = (const float*)d_in[1];
    const float* Wt = (const float*)d_in[2];
    float* out      = (float*)d_out;
    short* wfrag    = (short*)d_ws;   // needs 512 KB of workspace

    pack_weight<<<64, 256, 0, stream>>>(Wt, wfrag);
    fft_gemm<<<4096, 256, 0, stream>>>(R, I, wfrag, out);
}